// Round 1
// baseline (253.484 us; speedup 1.0000x reference)
//
#include <hip/hip_runtime.h>
#include <hip/hip_bf16.h>
#include <stdint.h>

#define D_MODEL 1024
#define NHEADS  16
#define HDIM    64
#define SEQ     1024
#define BATCH   8

typedef __bf16 bf16;
typedef bf16  bf16x8 __attribute__((ext_vector_type(8)));
typedef float f32x4  __attribute__((ext_vector_type(4)));

// swizzle for 64-element (128B) bf16 rows: spreads the 8 16B slots across banks
__device__ __forceinline__ int swzi(int row, int col) {
    return (row << 6) + (col ^ ((row & 7) << 3));
}

// ---------------- fp32 -> bf16 convert ----------------
__global__ void cvt_kernel(const float* __restrict__ in, bf16* __restrict__ out, int n) {
    int i = (blockIdx.x * 256 + threadIdx.x) * 8;
    if (i >= n) return;
    float4 a = *reinterpret_cast<const float4*>(in + i);
    float4 b = *reinterpret_cast<const float4*>(in + i + 4);
    union { bf16 h[8]; uint4 u; } pk;
    pk.h[0] = (bf16)a.x; pk.h[1] = (bf16)a.y; pk.h[2] = (bf16)a.z; pk.h[3] = (bf16)a.w;
    pk.h[4] = (bf16)b.x; pk.h[5] = (bf16)b.y; pk.h[6] = (bf16)b.z; pk.h[7] = (bf16)b.w;
    *reinterpret_cast<uint4*>(out + i) = pk.u;
}

// ---------------- shared GEMM core: C[128x128] tile, NT (both K-contiguous) ----------------
// A: [M,K] bf16 row-major; B: [N,K] bf16 row-major. K multiple of 64.
__device__ __forceinline__ void gemm_tile_acc(
    const bf16* __restrict__ A, const bf16* __restrict__ B, int K,
    int m0, int n0, bf16* As, bf16* Bs,
    f32x4 acc[4][4], int wr, int wc, int lane, int tid)
{
    for (int kt = 0; kt < K; kt += 64) {
        __syncthreads();
        // stage A,B tiles [128 rows][64 cols] with swizzle
#pragma unroll
        for (int c = 0; c < 4; ++c) {
            int chunk = tid + c * 256;          // 0..1023
            int r   = chunk >> 3;
            int col = (chunk & 7) << 3;
            uint4 va = *reinterpret_cast<const uint4*>(A + (size_t)(m0 + r) * K + kt + col);
            uint4 vb = *reinterpret_cast<const uint4*>(B + (size_t)(n0 + r) * K + kt + col);
            *reinterpret_cast<uint4*>(As + swzi(r, col)) = va;
            *reinterpret_cast<uint4*>(Bs + swzi(r, col)) = vb;
        }
        __syncthreads();
#pragma unroll
        for (int kk = 0; kk < 2; ++kk) {
            bf16x8 af[4], bfr[4];
#pragma unroll
            for (int t = 0; t < 4; ++t) {
                af[t]  = *reinterpret_cast<const bf16x8*>(As + swzi(wr * 64 + t * 16 + (lane & 15), kk * 32 + ((lane >> 4) << 3)));
                bfr[t] = *reinterpret_cast<const bf16x8*>(Bs + swzi(wc * 64 + t * 16 + (lane & 15), kk * 32 + ((lane >> 4) << 3)));
            }
#pragma unroll
            for (int i = 0; i < 4; ++i)
#pragma unroll
                for (int j = 0; j < 4; ++j)
                    acc[i][j] = __builtin_amdgcn_mfma_f32_16x16x32_bf16(af[i], bfr[j], acc[i][j], 0, 0, 0);
        }
    }
}

// ---------------- QKV GEMM: out cols 0..3071 -> q/k/v [BH][SEQ][HDIM] bf16 ----------------
__global__ __launch_bounds__(256)
void qkv_gemm(const bf16* __restrict__ X, const bf16* __restrict__ W,
              const float* __restrict__ bias,
              bf16* __restrict__ q_ws, bf16* __restrict__ k_ws, bf16* __restrict__ v_ws)
{
    __shared__ __align__(16) bf16 As[128 * 64];
    __shared__ __align__(16) bf16 Bs[128 * 64];
    const int NB = 3072 / 128;                  // 24
    int bm = blockIdx.x / NB, bn = blockIdx.x % NB;
    int m0 = bm * 128, n0 = bn * 128;
    int tid = threadIdx.x, lane = tid & 63, w = tid >> 6;
    int wr = w >> 1, wc = w & 1;
    f32x4 acc[4][4];
#pragma unroll
    for (int i = 0; i < 4; ++i)
#pragma unroll
        for (int j = 0; j < 4; ++j) acc[i][j] = (f32x4){0.f, 0.f, 0.f, 0.f};

    gemm_tile_acc(X, W, 1024, m0, n0, As, Bs, acc, wr, wc, lane, tid);

#pragma unroll
    for (int i = 0; i < 4; ++i) {
        int mbase = m0 + wr * 64 + i * 16 + ((lane >> 4) << 2);
#pragma unroll
        for (int j = 0; j < 4; ++j) {
            int col = n0 + wc * 64 + j * 16 + (lane & 15);
            int which = col >> 10, rem = col & 1023;
            int h = rem >> 6, d = rem & 63;
            float bi = bias[col];
#pragma unroll
            for (int r = 0; r < 4; ++r) {
                int m = mbase + r;
                int b = m >> 10, nrow = m & 1023;
                float v = acc[i][j][r] + bi;
                size_t off = ((size_t)(b * NHEADS + h) * SEQ + nrow) * HDIM + d;
                if (which == 0)      q_ws[off] = (bf16)(v * 0.125f);   // fold softmax scale
                else if (which == 1) k_ws[off] = (bf16)v;
                else                 v_ws[off] = (bf16)v;
            }
        }
    }
}

// ---------------- proj GEMM: [8192,1024]bf16 @ [1024,1024]bf16^T + bias -> fp32 ----------------
__global__ __launch_bounds__(256)
void proj_gemm(const bf16* __restrict__ Ao, const bf16* __restrict__ W,
               const float* __restrict__ bias, float* __restrict__ out)
{
    __shared__ __align__(16) bf16 As[128 * 64];
    __shared__ __align__(16) bf16 Bs[128 * 64];
    const int NB = 1024 / 128;                  // 8
    int bm = blockIdx.x / NB, bn = blockIdx.x % NB;
    int m0 = bm * 128, n0 = bn * 128;
    int tid = threadIdx.x, lane = tid & 63, w = tid >> 6;
    int wr = w >> 1, wc = w & 1;
    f32x4 acc[4][4];
#pragma unroll
    for (int i = 0; i < 4; ++i)
#pragma unroll
        for (int j = 0; j < 4; ++j) acc[i][j] = (f32x4){0.f, 0.f, 0.f, 0.f};

    gemm_tile_acc(Ao, W, 1024, m0, n0, As, Bs, acc, wr, wc, lane, tid);

#pragma unroll
    for (int i = 0; i < 4; ++i) {
        int mbase = m0 + wr * 64 + i * 16 + ((lane >> 4) << 2);
#pragma unroll
        for (int j = 0; j < 4; ++j) {
            int col = n0 + wc * 64 + j * 16 + (lane & 15);
            float bi = bias[col];
#pragma unroll
            for (int r = 0; r < 4; ++r) {
                int m = mbase + r;
                out[(size_t)m * D_MODEL + col] = acc[i][j][r] + bi;
            }
        }
    }
}

// ---------------- flash attention: 1 block = (bh, 64 q-rows), 4 waves x 16 rows ----------------
__device__ __forceinline__ float red16_max(float v) {
    v = fmaxf(v, __shfl_xor(v, 1));
    v = fmaxf(v, __shfl_xor(v, 2));
    v = fmaxf(v, __shfl_xor(v, 4));
    v = fmaxf(v, __shfl_xor(v, 8));
    return v;
}
__device__ __forceinline__ float red16_sum(float v) {
    v += __shfl_xor(v, 1);
    v += __shfl_xor(v, 2);
    v += __shfl_xor(v, 4);
    v += __shfl_xor(v, 8);
    return v;
}

__global__ __launch_bounds__(256)
void attn_kernel(const bf16* __restrict__ Q, const bf16* __restrict__ K,
                 const bf16* __restrict__ V, bf16* __restrict__ AO)
{
    __shared__ __align__(16) bf16 kl[64 * 64];
    __shared__ __align__(16) bf16 vl[64 * 64];
    __shared__ __align__(16) bf16 pl[4][16 * 64];
    int bh = blockIdx.x & 127;
    int qt = blockIdx.x >> 7;                   // 0..15
    int tid = threadIdx.x, lane = tid & 63, w = tid >> 6;
    const bf16* Qb = Q + (size_t)bh * SEQ * HDIM;
    const bf16* Kb = K + (size_t)bh * SEQ * HDIM;
    const bf16* Vb = V + (size_t)bh * SEQ * HDIM;

    // Q fragments (A-operand), rows qt*64 + w*16 + (lane&15)
    int qrow = qt * 64 + w * 16 + (lane & 15);
    bf16x8 qf[2];
#pragma unroll
    for (int kk = 0; kk < 2; ++kk)
        qf[kk] = *reinterpret_cast<const bf16x8*>(Qb + (size_t)qrow * HDIM + kk * 32 + ((lane >> 4) << 3));

    f32x4 o[4];
    float mrun[4], lrun[4];
#pragma unroll
    for (int dt = 0; dt < 4; ++dt) o[dt] = (f32x4){0.f, 0.f, 0.f, 0.f};
#pragma unroll
    for (int r = 0; r < 4; ++r) { mrun[r] = -1e30f; lrun[r] = 0.f; }

    bf16* myp = pl[w];

    for (int t = 0; t < 16; ++t) {
        __syncthreads();
        // stage K,V tiles [64 keys][64 d] swizzled
#pragma unroll
        for (int c = 0; c < 2; ++c) {
            int chunk = tid + c * 256;          // 0..511
            int r   = chunk >> 3;
            int col = (chunk & 7) << 3;
            uint4 vk = *reinterpret_cast<const uint4*>(Kb + (size_t)(t * 64 + r) * HDIM + col);
            uint4 vv = *reinterpret_cast<const uint4*>(Vb + (size_t)(t * 64 + r) * HDIM + col);
            *reinterpret_cast<uint4*>(kl + swzi(r, col)) = vk;
            *reinterpret_cast<uint4*>(vl + swzi(r, col)) = vv;
        }
        __syncthreads();

        // S = Q K^T  (16 q-rows x 64 keys per wave)
        f32x4 s[4];
#pragma unroll
        for (int nt = 0; nt < 4; ++nt) {
            s[nt] = (f32x4){0.f, 0.f, 0.f, 0.f};
#pragma unroll
            for (int kk = 0; kk < 2; ++kk) {
                bf16x8 kf = *reinterpret_cast<const bf16x8*>(
                    kl + swzi(nt * 16 + (lane & 15), kk * 32 + ((lane >> 4) << 3)));
                s[nt] = __builtin_amdgcn_mfma_f32_16x16x32_bf16(qf[kk], kf, s[nt], 0, 0, 0);
            }
        }

        // online softmax; lane holds rows (lane>>4)*4 + r, col (lane&15)+16*nt
        float p[4][4];
#pragma unroll
        for (int r = 0; r < 4; ++r) {
            float pm = fmaxf(fmaxf(s[0][r], s[1][r]), fmaxf(s[2][r], s[3][r]));
            pm = red16_max(pm);
            float mnew = fmaxf(mrun[r], pm);
            float alpha = __expf(mrun[r] - mnew);
            float psum = 0.f;
#pragma unroll
            for (int nt = 0; nt < 4; ++nt) {
                p[nt][r] = __expf(s[nt][r] - mnew);
                psum += p[nt][r];
            }
            psum = red16_sum(psum);
            lrun[r] = lrun[r] * alpha + psum;
            mrun[r] = mnew;
#pragma unroll
            for (int dt = 0; dt < 4; ++dt) o[dt][r] *= alpha;
        }

        // write P (bf16) to per-wave LDS in [qrow][key] layout
#pragma unroll
        for (int nt = 0; nt < 4; ++nt)
#pragma unroll
            for (int r = 0; r < 4; ++r)
                myp[swzi(((lane >> 4) << 2) + r, nt * 16 + (lane & 15))] = (bf16)p[nt][r];

        // PV: A-frags from P, B-frags from V (scalar column reads)
        bf16x8 pa[2];
#pragma unroll
        for (int ks = 0; ks < 2; ++ks)
            pa[ks] = *reinterpret_cast<const bf16x8*>(
                myp + swzi(lane & 15, ks * 32 + ((lane >> 4) << 3)));
#pragma unroll
        for (int dt = 0; dt < 4; ++dt) {
            int dcol = dt * 16 + (lane & 15);
#pragma unroll
            for (int ks = 0; ks < 2; ++ks) {
                bf16x8 vf;
#pragma unroll
                for (int e = 0; e < 8; ++e) {
                    int key = ks * 32 + ((lane >> 4) << 3) + e;
                    vf[e] = vl[swzi(key, dcol)];
                }
                o[dt] = __builtin_amdgcn_mfma_f32_16x16x32_bf16(pa[ks], vf, o[dt], 0, 0, 0);
            }
        }
    }

    // epilogue: normalize and store to [B][N][C] bf16
    int b = bh >> 4, h = bh & 15;
#pragma unroll
    for (int r = 0; r < 4; ++r) {
        float inv = 1.f / lrun[r];
        int row = qt * 64 + w * 16 + ((lane >> 4) << 2) + r;
#pragma unroll
        for (int dt = 0; dt < 4; ++dt) {
            int dcol = dt * 16 + (lane & 15);
            AO[((size_t)(b * SEQ) + row) * D_MODEL + h * HDIM + dcol] = (bf16)(o[dt][r] * inv);
        }
    }
}

// ---------------- launch ----------------
extern "C" void kernel_launch(void* const* d_in, const int* in_sizes, int n_in,
                              void* d_out, int out_size, void* d_ws, size_t ws_size,
                              hipStream_t stream) {
    const float* x      = (const float*)d_in[0];
    const float* qkv_w  = (const float*)d_in[1];
    const float* qkv_b  = (const float*)d_in[2];
    const float* proj_w = (const float*)d_in[3];
    const float* proj_b = (const float*)d_in[4];
    float* out = (float*)d_out;
    char* ws = (char*)d_ws;

    bf16* x_bf    = (bf16*)(ws);                      // 16 MB (8192*1024)
    bf16* wqkv_bf = (bf16*)(ws + (size_t)(16 << 20)); // 6 MB
    bf16* wproj_bf= (bf16*)(ws + (size_t)(22 << 20)); // 2 MB
    bf16* q_ws    = (bf16*)(ws + (size_t)(24 << 20)); // 16 MB
    bf16* k_ws    = (bf16*)(ws + (size_t)(40 << 20)); // 16 MB
    bf16* v_ws    = (bf16*)(ws + (size_t)(56 << 20)); // 16 MB
    bf16* ao_ws   = x_bf;                             // alias: x consumed after QKV GEMM

    cvt_kernel<<<(8192 * 1024) / 2048, 256, 0, stream>>>(x, x_bf, 8192 * 1024);
    cvt_kernel<<<(3072 * 1024) / 2048, 256, 0, stream>>>(qkv_w, wqkv_bf, 3072 * 1024);
    cvt_kernel<<<(1024 * 1024) / 2048, 256, 0, stream>>>(proj_w, wproj_bf, 1024 * 1024);

    qkv_gemm<<<64 * 24, 256, 0, stream>>>(x_bf, wqkv_bf, qkv_b, q_ws, k_ws, v_ws);
    attn_kernel<<<128 * 16, 256, 0, stream>>>(q_ws, k_ws, v_ws, ao_ws);
    proj_gemm<<<64 * 8, 256, 0, stream>>>(ao_ws, wproj_bf, proj_b, out);
}

// Round 2
// 188.606 us; speedup vs baseline: 1.3440x; 1.3440x over previous
//
#include <hip/hip_runtime.h>
#include <hip/hip_bf16.h>
#include <stdint.h>

#define D_MODEL 1024
#define NHEADS  16
#define HDIM    64
#define SEQ     1024
#define BATCH   8

typedef __bf16 bf16;
typedef bf16  bf16x8 __attribute__((ext_vector_type(8)));
typedef float f32x4  __attribute__((ext_vector_type(4)));
typedef uint32_t u32;

// swizzle for 64-element (128B) bf16 rows: XOR the 16B-chunk index with row&7
__device__ __forceinline__ int swzi(int row, int col) {
    return (row << 6) + (col ^ ((row & 7) << 3));
}

// async global->LDS, 16B per lane. LDS dest must be wave-uniform base + lane*16.
__device__ __forceinline__ void gload_lds16(const bf16* g, bf16* l) {
    __builtin_amdgcn_global_load_lds(
        (const __attribute__((address_space(1))) void*)g,
        (__attribute__((address_space(3))) void*)l, 16, 0, 0);
}

// ---------------- fp32 -> bf16 convert ----------------
__global__ void cvt_kernel(const float* __restrict__ in, bf16* __restrict__ out, int n) {
    int i = (blockIdx.x * 256 + threadIdx.x) * 8;
    if (i >= n) return;
    float4 a = *reinterpret_cast<const float4*>(in + i);
    float4 b = *reinterpret_cast<const float4*>(in + i + 4);
    union { bf16 h[8]; uint4 u; } pk;
    pk.h[0] = (bf16)a.x; pk.h[1] = (bf16)a.y; pk.h[2] = (bf16)a.z; pk.h[3] = (bf16)a.w;
    pk.h[4] = (bf16)b.x; pk.h[5] = (bf16)b.y; pk.h[6] = (bf16)b.z; pk.h[7] = (bf16)b.w;
    *reinterpret_cast<uint4*>(out + i) = pk.u;
}

// ---------------- shared GEMM core: C[128x128] tile, NT (both K-contiguous) --------------
// Staging: linear LDS via global_load_lds, source address pre-swizzled so that
// LDS element (r,c) holds global (r, c ^ ((r&7)<<3)); reads use swzi() as before.
__device__ __forceinline__ void gemm_tile_acc(
    const bf16* __restrict__ A, const bf16* __restrict__ B, int K,
    int m0, int n0, bf16* As, bf16* Bs,
    f32x4 acc[4][4], int wr, int wc, int lane, int tid)
{
    for (int kt = 0; kt < K; kt += 64) {
        __syncthreads();
#pragma unroll
        for (int c = 0; c < 4; ++c) {
            int chunk = tid + c * 256;          // 0..1023
            int r   = chunk >> 3;
            int j   = chunk & 7;
            int jg  = j ^ (r & 7);
            gload_lds16(A + (size_t)(m0 + r) * K + kt + jg * 8, As + chunk * 8);
            gload_lds16(B + (size_t)(n0 + r) * K + kt + jg * 8, Bs + chunk * 8);
        }
        __syncthreads();
#pragma unroll
        for (int kk = 0; kk < 2; ++kk) {
            bf16x8 af[4], bfr[4];
#pragma unroll
            for (int t = 0; t < 4; ++t) {
                af[t]  = *reinterpret_cast<const bf16x8*>(As + swzi(wr * 64 + t * 16 + (lane & 15), kk * 32 + ((lane >> 4) << 3)));
                bfr[t] = *reinterpret_cast<const bf16x8*>(Bs + swzi(wc * 64 + t * 16 + (lane & 15), kk * 32 + ((lane >> 4) << 3)));
            }
#pragma unroll
            for (int i = 0; i < 4; ++i)
#pragma unroll
                for (int j2 = 0; j2 < 4; ++j2)
                    acc[i][j2] = __builtin_amdgcn_mfma_f32_16x16x32_bf16(af[i], bfr[j2], acc[i][j2], 0, 0, 0);
        }
    }
}

// ---------------- QKV GEMM: cols 0..3071 -> q/k [BH][N][D], v transposed [BH][D][N] ------
__global__ __launch_bounds__(256)
void qkv_gemm(const bf16* __restrict__ X, const bf16* __restrict__ W,
              const float* __restrict__ bias,
              bf16* __restrict__ q_ws, bf16* __restrict__ k_ws, bf16* __restrict__ vt_ws)
{
    __shared__ __align__(16) bf16 As[128 * 64];
    __shared__ __align__(16) bf16 Bs[128 * 64];
    const int NB = 3072 / 128;                  // 24
    int bm = blockIdx.x / NB, bn = blockIdx.x % NB;
    int m0 = bm * 128, n0 = bn * 128;
    int tid = threadIdx.x, lane = tid & 63, w = tid >> 6;
    int wr = w >> 1, wc = w & 1;
    f32x4 acc[4][4];
#pragma unroll
    for (int i = 0; i < 4; ++i)
#pragma unroll
        for (int j = 0; j < 4; ++j) acc[i][j] = (f32x4){0.f, 0.f, 0.f, 0.f};

    gemm_tile_acc(X, W, 1024, m0, n0, As, Bs, acc, wr, wc, lane, tid);

#pragma unroll
    for (int i = 0; i < 4; ++i) {
        int mbase = m0 + wr * 64 + i * 16 + ((lane >> 4) << 2);
#pragma unroll
        for (int j = 0; j < 4; ++j) {
            int col = n0 + wc * 64 + j * 16 + (lane & 15);
            int which = col >> 10, rem = col & 1023;
            int h = rem >> 6, d = rem & 63;
            float bi = bias[col];
            int b = mbase >> 10, nrow0 = mbase & 1023;   // 4-row pack stays in one batch
            int bh = b * NHEADS + h;
            if (which == 2) {
                // transposed V: vt[bh][d][n], 4 consecutive n -> 8B packed store
                union { bf16 h4[4]; uint2 u; } vp;
#pragma unroll
                for (int r = 0; r < 4; ++r) vp.h4[r] = (bf16)(acc[i][j][r] + bi);
                *reinterpret_cast<uint2*>(vt_ws + ((size_t)bh * HDIM + d) * SEQ + nrow0) = vp.u;
            } else {
                bf16* dst = (which == 0) ? q_ws : k_ws;
                float scl = (which == 0) ? 0.125f : 1.0f;   // fold softmax scale into q
#pragma unroll
                for (int r = 0; r < 4; ++r) {
                    float v = (acc[i][j][r] + bi) * scl;
                    dst[((size_t)bh * SEQ + nrow0 + r) * HDIM + d] = (bf16)v;
                }
            }
        }
    }
}

// ---------------- proj GEMM: [8192,1024]bf16 @ [1024,1024]bf16^T + bias -> fp32 ----------
__global__ __launch_bounds__(256)
void proj_gemm(const bf16* __restrict__ Ao, const bf16* __restrict__ W,
               const float* __restrict__ bias, float* __restrict__ out)
{
    __shared__ __align__(16) bf16 As[128 * 64];
    __shared__ __align__(16) bf16 Bs[128 * 64];
    const int NB = 1024 / 128;                  // 8
    int bm = blockIdx.x / NB, bn = blockIdx.x % NB;
    int m0 = bm * 128, n0 = bn * 128;
    int tid = threadIdx.x, lane = tid & 63, w = tid >> 6;
    int wr = w >> 1, wc = w & 1;
    f32x4 acc[4][4];
#pragma unroll
    for (int i = 0; i < 4; ++i)
#pragma unroll
        for (int j = 0; j < 4; ++j) acc[i][j] = (f32x4){0.f, 0.f, 0.f, 0.f};

    gemm_tile_acc(Ao, W, 1024, m0, n0, As, Bs, acc, wr, wc, lane, tid);

#pragma unroll
    for (int i = 0; i < 4; ++i) {
        int mbase = m0 + wr * 64 + i * 16 + ((lane >> 4) << 2);
#pragma unroll
        for (int j = 0; j < 4; ++j) {
            int col = n0 + wc * 64 + j * 16 + (lane & 15);
            float bi = bias[col];
#pragma unroll
            for (int r = 0; r < 4; ++r)
                out[(size_t)(mbase + r) * D_MODEL + col] = acc[i][j][r] + bi;
        }
    }
}

// ---------------- flash attention, swapped-QK^T, register softmax --------------------
// Block = (bh, 64 q-rows), 4 waves x 16 q each. S^T = mfma(K, Q); lane owns q = lane&15,
// holds 16 P values (keys nt*16 + g*4 + r, g = lane>>4). PV computes O^T = V^T . P.
__global__ __launch_bounds__(256)
void attn_kernel(const bf16* __restrict__ Q, const bf16* __restrict__ K,
                 const bf16* __restrict__ Vt, bf16* __restrict__ AO)
{
    __shared__ __align__(16) bf16 kl[64 * 64];   // K tile  [key][d]  (swizzled content)
    __shared__ __align__(16) bf16 vl[64 * 64];   // V^T tile [d][key] (swizzled content)
    int bh = blockIdx.x & 127;
    int qt = blockIdx.x >> 7;                    // 0..15
    int tid = threadIdx.x, lane = tid & 63, w = tid >> 6;
    int g = lane >> 4, q = lane & 15;
    const bf16* Qb  = Q  + (size_t)bh * SEQ * HDIM;
    const bf16* Kb  = K  + (size_t)bh * SEQ * HDIM;
    const bf16* Vtb = Vt + (size_t)bh * HDIM * SEQ;

    // Q fragment (B-operand of swapped QK^T): lane holds q-row (qt*64+w*16+q), d slice
    int qrow = qt * 64 + w * 16 + q;
    bf16x8 qf[2];
#pragma unroll
    for (int kk = 0; kk < 2; ++kk)
        qf[kk] = *reinterpret_cast<const bf16x8*>(Qb + (size_t)qrow * HDIM + kk * 32 + (g << 3));

    f32x4 o[4];                                  // O^T: rows d = dt*16 + g*4 + r, col q
#pragma unroll
    for (int dt = 0; dt < 4; ++dt) o[dt] = (f32x4){0.f, 0.f, 0.f, 0.f};
    float mrun = -1e30f, lrun = 0.f;

    int srcA = ((g & 1) << 5) + q;               // lane holding keys (g&1)*8 .. +3 of nt_src
    int srcB = srcA + 16;                        // .. keys +4..7
    bool hi = (g >> 1) != 0;

    for (int t = 0; t < 16; ++t) {
        __syncthreads();
        // stage K tile [64 key][64 d] and V^T tile [64 d][64 key]; linear LDS,
        // pre-swizzled global source (chunk j reads global chunk j^(r&7))
#pragma unroll
        for (int c = 0; c < 2; ++c) {
            int chunk = tid + c * 256;           // 0..511
            int r  = chunk >> 3;
            int j  = chunk & 7;
            int jg = j ^ (r & 7);
            gload_lds16(Kb  + (size_t)(t * 64 + r) * HDIM + jg * 8, kl + chunk * 8);
            gload_lds16(Vtb + (size_t)r * SEQ + t * 64 + jg * 8,    vl + chunk * 8);
        }
        __syncthreads();

        // S^T = K . Q^T : s[nt][r] = S[key = nt*16 + g*4 + r][q]
        f32x4 s[4];
#pragma unroll
        for (int nt = 0; nt < 4; ++nt) {
            s[nt] = (f32x4){0.f, 0.f, 0.f, 0.f};
#pragma unroll
            for (int kk = 0; kk < 2; ++kk) {
                bf16x8 kf = *reinterpret_cast<const bf16x8*>(
                    kl + swzi(nt * 16 + q, kk * 32 + (g << 3)));
                s[nt] = __builtin_amdgcn_mfma_f32_16x16x32_bf16(kf, qf[kk], s[nt], 0, 0, 0);
            }
        }

        // online softmax across this tile's 64 keys for lane's q
        float pm = s[0][0];
#pragma unroll
        for (int nt = 0; nt < 4; ++nt)
#pragma unroll
            for (int r = 0; r < 4; ++r) pm = fmaxf(pm, s[nt][r]);
        pm = fmaxf(pm, __shfl_xor(pm, 16));
        pm = fmaxf(pm, __shfl_xor(pm, 32));
        float mnew  = fmaxf(mrun, pm);
        float alpha = __expf(mrun - mnew);

        u32 pk[4][2];
        float psum = 0.f;
#pragma unroll
        for (int nt = 0; nt < 4; ++nt)
#pragma unroll
            for (int half = 0; half < 2; ++half) {
                float pa = __expf(s[nt][2 * half]     - mnew);
                float pb = __expf(s[nt][2 * half + 1] - mnew);
                psum += pa + pb;
                union { bf16 h[2]; u32 u; } pw;
                pw.h[0] = (bf16)pa; pw.h[1] = (bf16)pb;
                pk[nt][half] = pw.u;
            }
        psum += __shfl_xor(psum, 16);
        psum += __shfl_xor(psum, 32);
        lrun = lrun * alpha + psum;
        mrun = mnew;
#pragma unroll
        for (int dt = 0; dt < 4; ++dt) o[dt] *= alpha;

        // PV: O^T += V^T . P ; rebuild B-fragment (P[key][q]) from pk via bpermute
#pragma unroll
        for (int ks = 0; ks < 2; ++ks) {
            union { u32 u[4]; bf16x8 v; } pb;
            u32 a0 = __shfl((int)pk[2 * ks][0],     srcA);
            u32 a1 = __shfl((int)pk[2 * ks + 1][0], srcA);
            pb.u[0] = hi ? a1 : a0;
            u32 b0 = __shfl((int)pk[2 * ks][1],     srcA);
            u32 b1 = __shfl((int)pk[2 * ks + 1][1], srcA);
            pb.u[1] = hi ? b1 : b0;
            u32 c0 = __shfl((int)pk[2 * ks][0],     srcB);
            u32 c1 = __shfl((int)pk[2 * ks + 1][0], srcB);
            pb.u[2] = hi ? c1 : c0;
            u32 d0 = __shfl((int)pk[2 * ks][1],     srcB);
            u32 d1 = __shfl((int)pk[2 * ks + 1][1], srcB);
            pb.u[3] = hi ? d1 : d0;
#pragma unroll
            for (int dt = 0; dt < 4; ++dt) {
                bf16x8 vfr = *reinterpret_cast<const bf16x8*>(
                    vl + swzi(dt * 16 + q, ks * 32 + (g << 3)));
                o[dt] = __builtin_amdgcn_mfma_f32_16x16x32_bf16(vfr, pb.v, o[dt], 0, 0, 0);
            }
        }
    }

    // epilogue: O^T -> AO[b][n][h*64+d], normalize; 4 consecutive d -> 8B packed store
    int b = bh >> 4, h = bh & 15;
    float inv = 1.f / lrun;
    size_t base = ((size_t)b * SEQ + qrow) * D_MODEL + h * HDIM;
#pragma unroll
    for (int dt = 0; dt < 4; ++dt) {
        union { bf16 h4[4]; uint2 u; } ob;
#pragma unroll
        for (int r = 0; r < 4; ++r) ob.h4[r] = (bf16)(o[dt][r] * inv);
        *reinterpret_cast<uint2*>(AO + base + dt * 16 + (g << 2)) = ob.u;
    }
}

// ---------------- launch ----------------
extern "C" void kernel_launch(void* const* d_in, const int* in_sizes, int n_in,
                              void* d_out, int out_size, void* d_ws, size_t ws_size,
                              hipStream_t stream) {
    const float* x      = (const float*)d_in[0];
    const float* qkv_w  = (const float*)d_in[1];
    const float* qkv_b  = (const float*)d_in[2];
    const float* proj_w = (const float*)d_in[3];
    const float* proj_b = (const float*)d_in[4];
    float* out = (float*)d_out;
    char* ws = (char*)d_ws;

    bf16* x_bf    = (bf16*)(ws);                      // 16 MB (8192*1024)
    bf16* wqkv_bf = (bf16*)(ws + (size_t)(16 << 20)); // 6 MB
    bf16* wproj_bf= (bf16*)(ws + (size_t)(22 << 20)); // 2 MB
    bf16* q_ws    = (bf16*)(ws + (size_t)(24 << 20)); // 16 MB
    bf16* k_ws    = (bf16*)(ws + (size_t)(40 << 20)); // 16 MB
    bf16* vt_ws   = (bf16*)(ws + (size_t)(56 << 20)); // 16 MB (transposed V)
    bf16* ao_ws   = x_bf;                             // alias: x consumed after QKV GEMM

    cvt_kernel<<<(8192 * 1024) / 2048, 256, 0, stream>>>(x, x_bf, 8192 * 1024);
    cvt_kernel<<<(3072 * 1024) / 2048, 256, 0, stream>>>(qkv_w, wqkv_bf, 3072 * 1024);
    cvt_kernel<<<(1024 * 1024) / 2048, 256, 0, stream>>>(proj_w, wproj_bf, 1024 * 1024);

    qkv_gemm<<<64 * 24, 256, 0, stream>>>(x_bf, wqkv_bf, qkv_b, q_ws, k_ws, vt_ws);
    attn_kernel<<<128 * 16, 256, 0, stream>>>(q_ws, k_ws, vt_ws, ao_ws);
    proj_gemm<<<64 * 8, 256, 0, stream>>>(ao_ws, wproj_bf, proj_b, out);
}